// Round 14
// baseline (175.633 us; speedup 1.0000x reference)
//
#include <hip/hip_runtime.h>
#include <hip/hip_bf16.h>

#define N_NODES 4096
#define N_EDGES 8192
#define N_GRAPHS 64
#define HDIM 128

typedef __attribute__((ext_vector_type(8))) short bf16x8;
typedef __attribute__((ext_vector_type(4))) float f32x4;

static __device__ __forceinline__ unsigned short f2bf(float f) {
    unsigned u = __builtin_bit_cast(unsigned, f);
    u += 0x7fffu + ((u >> 16) & 1u);
    return (unsigned short)(u >> 16);
}
static __device__ __forceinline__ float bf2f(unsigned short s) {
    unsigned u = ((unsigned)s) << 16;
    return __builtin_bit_cast(float, u);
}

// ---------------- fused pre+edge: ONE dispatch.
// grid 1024: [0,512) edge MLP l1+l2+l3 (16 edges each, MFMA, on-the-fly B-frags);
//            [512,768) node MLP (+hb bias path);
//            [768,896) w4 pack -> SWIZZLED bf16 [o>>5:4][chunk:128][o&31:32][k^((o&7)<<3):128]
//                      (8192 B/chunk-slice: exactly 2 clean 256x16B global_load_lds sweeps;
//                       XOR swizzle on both sides replaces the k-pad for bank-conflict-free reads);
//            [896,1024) zero agg+cnt.
__global__ __launch_bounds__(256) void fused_pre_edge_kernel(
    const float* __restrict__ x, const float* __restrict__ p1w, const float* __restrict__ p1b,
    const float* __restrict__ p2w, const float* __restrict__ p2b, const float* __restrict__ e4b,
    unsigned short* __restrict__ h_bf, float* __restrict__ hb,
    const float* __restrict__ ea, const float* __restrict__ w1, const float* __restrict__ b1,
    const float* __restrict__ w2, const float* __restrict__ b2,
    const float* __restrict__ w3, const float* __restrict__ b3,
    unsigned short* __restrict__ e3bf,
    const float* __restrict__ w4, unsigned short* __restrict__ w4perm,
    float* __restrict__ aggz)
{
    __shared__ __align__(16) char smem[33024];
    const int t = threadIdx.x;
    const int bid = blockIdx.x;

    if (bid < 512) {
        // ---- edge MLP: l1 in-block (5->128 relu, LDS bf16), l2 (128->256 relu, MFMA),
        //      l3 (256->128 relu, MFMA). B-frags converted f32->bf16 on the fly.
        float (*es)[5] = (float(*)[5])smem;                        // 320 B
        unsigned short* l1a = (unsigned short*)(smem + 320);       // [16][136] bf16
        unsigned short* l2a = (unsigned short*)(smem + 4672);      // [16][264] bf16
        const int w = t >> 6, lane = t & 63, q = lane >> 4, l15 = lane & 15;
        const int e0 = bid * 16;
        const f32x4 zero4 = (f32x4){0.f, 0.f, 0.f, 0.f};

        for (int r = t; r < 80; r += 256) es[r / 5][r % 5] = ea[e0 * 5 + r];
        __syncthreads();
        {
            int j = t & 127, eh = t >> 7;
            float wd[5];
            #pragma unroll
            for (int d = 0; d < 5; ++d) wd[d] = w1[d * 128 + j];
            float bj = b1[j];
            #pragma unroll
            for (int p = 0; p < 8; ++p) {
                int e = eh * 8 + p;
                float acc = bj;
                #pragma unroll
                for (int d = 0; d < 5; ++d) acc += es[e][d] * wd[d];
                l1a[e * 136 + j] = f2bf(fmaxf(acc, 0.f));
            }
        }
        __syncthreads();

        bf16x8 afrag[4];
        #pragma unroll
        for (int s = 0; s < 4; ++s)
            afrag[s] = *(const bf16x8*)&l1a[l15 * 136 + s * 32 + q * 8];

        f32x4 acc[4];
        #pragma unroll
        for (int ob = 0; ob < 4; ++ob) acc[ob] = zero4;
        #pragma unroll
        for (int ob = 0; ob < 4; ++ob) {
            const int o = w * 64 + ob * 16 + l15;
            bf16x8 bfrag[4];
            #pragma unroll
            for (int s = 0; s < 4; ++s) {
                const int kb = s * 32 + q * 8;
                #pragma unroll
                for (int kk = 0; kk < 8; ++kk)
                    bfrag[s][kk] = (short)f2bf(w2[(kb + kk) * 256 + o]);
            }
            f32x4 tmp = __builtin_amdgcn_mfma_f32_16x16x32_bf16(afrag[0], bfrag[0], zero4, 0, 0, 0);
            tmp = __builtin_amdgcn_mfma_f32_16x16x32_bf16(afrag[1], bfrag[1], tmp, 0, 0, 0);
            tmp = __builtin_amdgcn_mfma_f32_16x16x32_bf16(afrag[2], bfrag[2], tmp, 0, 0, 0);
            acc[ob] = __builtin_amdgcn_mfma_f32_16x16x32_bf16(afrag[3], bfrag[3], tmp, 0, 0, 0);
        }
        #pragma unroll
        for (int ob = 0; ob < 4; ++ob) {
            int o = w * 64 + ob * 16 + l15;
            float bo = b2[o];
            #pragma unroll
            for (int r = 0; r < 4; ++r) {
                int e_loc = q * 4 + r;
                l2a[e_loc * 264 + o] = f2bf(fmaxf(acc[ob][r] + bo, 0.f));
            }
        }
        __syncthreads();

        f32x4 acc3[2];
        acc3[0] = zero4; acc3[1] = zero4;
        #pragma unroll
        for (int ks = 0; ks < 8; ++ks) {
            bf16x8 a3 = *(const bf16x8*)&l2a[l15 * 264 + ks * 32 + q * 8];
            #pragma unroll
            for (int ob = 0; ob < 2; ++ob) {
                const int o = w * 32 + ob * 16 + l15;
                bf16x8 bf;
                const int kb = ks * 32 + q * 8;
                #pragma unroll
                for (int kk = 0; kk < 8; ++kk)
                    bf[kk] = (short)f2bf(w3[(kb + kk) * 128 + o]);
                acc3[ob] = __builtin_amdgcn_mfma_f32_16x16x32_bf16(a3, bf, acc3[ob], 0, 0, 0);
            }
        }
        #pragma unroll
        for (int ob = 0; ob < 2; ++ob) {
            int o = w * 32 + ob * 16 + l15;
            float bo = b3[o];
            #pragma unroll
            for (int r = 0; r < 4; ++r) {
                int e = e0 + q * 4 + r;
                e3bf[(size_t)e * 128 + o] = f2bf(fmaxf(acc3[ob][r] + bo, 0.f));
            }
        }
    } else if (bid < 768) {
        // ---- node MLP: h = relu(x@p1+b1)@p2+b2 ; hb = h @ B4
        float (*xs)[11]  = (float(*)[11])smem;           // 704 B
        float (*l1t)[16] = (float(*)[16])(smem + 704);   // 8192 B
        float (*hs)[16]  = (float(*)[16])(smem + 8896);  // 8192 B
        const int nb = bid - 512;

        for (int r = t; r < 16 * 11; r += 256) {
            int e = r / 11, d = r % 11;
            xs[e][d] = x[(nb * 16 + e) * 11 + d];
        }
        __syncthreads();
        {
            int j = t & 127;
            float wd[11];
            #pragma unroll
            for (int d = 0; d < 11; ++d) wd[d] = p1w[d * 128 + j];
            float bj = p1b[j];
            for (int p = 0; p < 8; ++p) {
                int e = p * 2 + (t >> 7);
                float acc = bj;
                #pragma unroll
                for (int d = 0; d < 11; ++d) acc += xs[e][d] * wd[d];
                l1t[j][e] = fmaxf(acc, 0.f);
            }
        }
        __syncthreads();
        {
            int j = t & 127, eh = t >> 7;
            float acc[8];
            float bj = p2b[j];
            #pragma unroll
            for (int r = 0; r < 8; ++r) acc[r] = bj;
            #pragma unroll 8
            for (int k = 0; k < 128; ++k) {
                float w = p2w[k * 128 + j];
                const float4* row = (const float4*)&l1t[k][eh * 8];
                float4 v0 = row[0], v1 = row[1];
                acc[0] += v0.x * w; acc[1] += v0.y * w; acc[2] += v0.z * w; acc[3] += v0.w * w;
                acc[4] += v1.x * w; acc[5] += v1.y * w; acc[6] += v1.z * w; acc[7] += v1.w * w;
            }
            #pragma unroll
            for (int r = 0; r < 8; ++r) {
                int e = eh * 8 + r;
                h_bf[(nb * 16 + e) * 128 + j] = f2bf(acc[r]);
                hs[j][e] = acc[r];
            }
        }
        __syncthreads();
        {
            int j = t & 127, eh = t >> 7;
            float acc[8] = {0.f,0.f,0.f,0.f,0.f,0.f,0.f,0.f};
            #pragma unroll 8
            for (int i = 0; i < 128; ++i) {
                float w = e4b[i * 128 + j];
                const float4* row = (const float4*)&hs[i][eh * 8];
                float4 v0 = row[0], v1 = row[1];
                acc[0] += v0.x * w; acc[1] += v0.y * w; acc[2] += v0.z * w; acc[3] += v0.w * w;
                acc[4] += v1.x * w; acc[5] += v1.y * w; acc[6] += v1.z * w; acc[7] += v1.w * w;
            }
            #pragma unroll
            for (int r = 0; r < 8; ++r) hb[(nb * 16 + eh * 8 + r) * 128 + j] = acc[r];
        }
    } else if (bid < 896) {
        // ---- pack e4_w: SWIZZLED bf16 [o>>5][chunk i][o&31][k ^ ((o&7)<<3)], 4096 u16/slice
        unsigned short (*tt)[129] = (unsigned short(*)[129])smem;  // 33024 B
        const int i = bid - 768;
        for (int r = t; r < 16384; r += 256) {
            int k = r >> 7, o = r & 127;
            tt[o][k] = f2bf(w4[k * 16384 + i * 128 + o]);
        }
        __syncthreads();
        for (int r = t; r < 16384; r += 256) {
            int o = r >> 7, k = r & 127;
            w4perm[((size_t)(o >> 5) * 128 + i) * 4096
                   + (size_t)(o & 31) * 128 + (k ^ ((o & 7) << 3))] = tt[o][k];
        }
    } else {
        // ---- zero agg (2 MB) + cnt (16 KB), contiguous: 132096 float4
        float4* dst = (float4*)aggz;
        const float4 z = make_float4(0.f, 0.f, 0.f, 0.f);
        for (int i = (bid - 896) * 256 + t; i < 132096; i += 128 * 256) dst[i] = z;
    }
}

// ---------------- fused NNConv message GEMM, v11: T3/T4 counted-vmcnt LDS pipeline.
// block = 128 edges x 32 o x 64 chunks (K-half). grid 512: bid&7 = XCD = (osplit,ksplit)
// -> 512 KB B-slice L2-resident. B staged to LDS via global_load_lds into a 4-deep ring
// (8 KB/chunk, 2 clean full-block sweeps), staged 2 chunks AHEAD; per chunk:
// s_waitcnt vmcnt(4) (counted — 2 stages stay in flight across the barrier, never 0 in
// the main loop) + ONE raw s_barrier + 64 block-wide MFMA under s_setprio (T5).
// B reads use the pack-side XOR swizzle -> 2-way bank aliasing (free).
__global__ __launch_bounds__(256, 2) void nnconv_kernel(
    const unsigned short* __restrict__ e3bf, const unsigned short* __restrict__ h_bf,
    const unsigned short* __restrict__ w4perm, const float* __restrict__ hb,
    const int* __restrict__ ei, float* __restrict__ agg, float* __restrict__ cnt)
{
    __shared__ __align__(16) float ht_f[64 * 128];          // [i_local:64][e:128] f32, 32 KB
    __shared__ __align__(16) unsigned short ldsB[4 * 4096]; // 4-deep ring, 8 KB/chunk, 32 KB
    const int t = threadIdx.x;
    const int bid = blockIdx.x;
    const int xcd    = bid & 7;
    const int osplit = xcd >> 1;         // 4 o-slices of 32
    const int ksplit = xcd & 1;          // 2 K-halves of 64 chunks
    const int etile  = bid >> 3;         // 64 tiles of 128 edges
    const int w = t >> 6, lane = t & 63, q = lane >> 4, l15 = lane & 15;
    const int mg = w >> 1;               // edge-group: mg*64
    const int og = w & 1;                // o-group within slice: og*16
    const int e0 = etile * 128;
    const int o0 = osplit * 32;
    const int k0 = ksplit * 64;          // first chunk of this block's K-half
    const int oloc = og * 16 + l15;      // 0..31
    const int oswz = (oloc & 7) << 3;    // read-side XOR (matches pack)

    // stage one chunk slice (8192 B contiguous) into ring buf: 2 full 256x16B sweeps.
    auto stage = [&](int buf, int gi) {
        const char* src = (const char*)(w4perm + ((size_t)osplit * 128 + gi) * 4096);
        char* dst = (char*)ldsB + buf * 8192;
        __builtin_amdgcn_global_load_lds(
            (const __attribute__((address_space(1))) unsigned int*)(src + t * 16),
            (__attribute__((address_space(3))) unsigned int*)(dst + t * 16), 16, 0, 0);
        __builtin_amdgcn_global_load_lds(
            (const __attribute__((address_space(1))) unsigned int*)(src + 4096 + t * 16),
            (__attribute__((address_space(3))) unsigned int*)(dst + 4096 + t * 16), 16, 0, 0);
    };

    stage(0, k0);        // prefetch chunks 0,1 (overlap afrag + gather)
    stage(1, k0 + 1);

    // A fragments: this wave's 64 e3 rows (full K=128), constant across all chunks.
    bf16x8 afrag[4][4];
    #pragma unroll
    for (int mb = 0; mb < 4; ++mb)
        #pragma unroll
        for (int s = 0; s < 4; ++s) {
            int row = e0 + mg * 64 + mb * 16 + l15;
            afrag[mb][s] = *(const bf16x8*)(e3bf + (size_t)row * 128 + s * 32 + q * 8);
        }
    #pragma unroll
    for (int mb = 0; mb < 4; ++mb)
        #pragma unroll
        for (int s = 0; s < 4; ++s)
            asm volatile("" : "+v"(afrag[mb][s]));
    asm volatile("" ::: "memory");

    {   // gather h rows through src[e]: 2 threads/edge, this K-half (64 i), f32 transposed
        int r = t >> 1, part = t & 1;
        int s = ei[e0 + r];
        #pragma unroll
        for (int u = 0; u < 4; ++u) {
            uint4 v = *(const uint4*)(h_bf + (size_t)s * 128 + k0 + part * 32 + u * 8);
            const unsigned short* pv = (const unsigned short*)&v;
            #pragma unroll
            for (int j = 0; j < 8; ++j)
                ht_f[(part * 32 + u * 8 + j) * 128 + r] = bf2f(pv[j]);
        }
    }

    f32x4 acc[4];
    #pragma unroll
    for (int mb = 0; mb < 4; ++mb) acc[mb] = (f32x4){0.f, 0.f, 0.f, 0.f};
    const f32x4 zero4 = (f32x4){0.f, 0.f, 0.f, 0.f};

    __syncthreads();   // ht_f ready (also drains prologue stages 0,1)

    auto compute = [&](int bufu16, int ci) {
        bf16x8 bfrag[4];
        #pragma unroll
        for (int s = 0; s < 4; ++s) {
            int kb = s * 32 + q * 8;
            bfrag[s] = *(const bf16x8*)&ldsB[bufu16 + oloc * 128 + (kb ^ oswz)];
        }
        __builtin_amdgcn_s_setprio(1);
        #pragma unroll
        for (int mb = 0; mb < 4; ++mb) {
            f32x4 hv = *(const f32x4*)&ht_f[ci * 128 + mg * 64 + mb * 16 + q * 4];
            f32x4 tmp = __builtin_amdgcn_mfma_f32_16x16x32_bf16(afrag[mb][0], bfrag[0], zero4, 0, 0, 0);
            tmp = __builtin_amdgcn_mfma_f32_16x16x32_bf16(afrag[mb][1], bfrag[1], tmp, 0, 0, 0);
            tmp = __builtin_amdgcn_mfma_f32_16x16x32_bf16(afrag[mb][2], bfrag[2], tmp, 0, 0, 0);
            tmp = __builtin_amdgcn_mfma_f32_16x16x32_bf16(afrag[mb][3], bfrag[3], tmp, 0, 0, 0);
            #pragma unroll
            for (int r = 0; r < 4; ++r)
                acc[mb][r] += hv[r] * tmp[r];
        }
        __builtin_amdgcn_s_setprio(0);
    };

    // Main loop: stage 2 ahead; counted vmcnt(4) keeps 2 stages in flight across the
    // barrier (never drains to 0). 4-buf ring: writer distance 3, in-flight 1-2, reader 0.
    for (int c = 0; c < 62; ++c) {
        stage((c + 2) & 3, k0 + c + 2);
        asm volatile("s_waitcnt vmcnt(4)" ::: "memory");
        __builtin_amdgcn_s_barrier();
        compute((c & 3) * 4096, c);
    }
    asm volatile("s_waitcnt vmcnt(2)" ::: "memory");
    __builtin_amdgcn_s_barrier();
    compute((62 & 3) * 4096, 62);
    asm volatile("s_waitcnt vmcnt(0)" ::: "memory");
    __builtin_amdgcn_s_barrier();
    compute((63 & 3) * 4096, 63);

    // epilogue: ONE atomic per (e,o) per K-half (2.1M total). ksplit 0 adds hb bias;
    // (xcd,og,l15)==0 lanes count degree.
    #pragma unroll
    for (int mb = 0; mb < 4; ++mb) {
        #pragma unroll
        for (int r = 0; r < 4; ++r) {
            int e = e0 + mg * 64 + mb * 16 + q * 4 + r;
            int de = ei[N_EDGES + e];
            int se = ei[e];
            int o = o0 + oloc;
            float v = acc[mb][r];
            if (ksplit == 0) v += hb[(size_t)se * 128 + o];
            if (xcd == 0 && og == 0 && l15 == 0) atomicAdd(&cnt[de], 1.0f);
            atomicAdd(&agg[(size_t)de * 128 + o], v);
        }
    }
}

// ---------------- scatter-mean finalize + global add pool.
// batch is SORTED -> one block per graph, binary-search bounds, direct store.
__global__ __launch_bounds__(512) void pool_kernel(
    const float* __restrict__ agg, const float* __restrict__ cnt,
    const int* __restrict__ batch, float* __restrict__ out)
{
    __shared__ float ps[4][128];
    const int g = blockIdx.x;
    const int ch = threadIdx.x & 127, th = threadIdx.x >> 7;
    int lo = 0, hi = N_NODES;
    while (lo < hi) { int m = (lo + hi) >> 1; if (batch[m] < g) lo = m + 1; else hi = m; }
    const int n_lo = lo;
    int lo2 = n_lo, hi2 = N_NODES;
    while (lo2 < hi2) { int m = (lo2 + hi2) >> 1; if (batch[m] < g + 1) lo2 = m + 1; else hi2 = m; }
    const int n_hi = lo2;

    float s = 0.f;
    for (int n = n_lo + th; n < n_hi; n += 4) {
        float c = cnt[n];
        c = c > 1.f ? c : 1.f;
        s += agg[n * 128 + ch] / c;
    }
    ps[th][ch] = s;
    __syncthreads();
    if (th == 0)
        out[g * 128 + ch] = (ps[0][ch] + ps[1][ch]) + (ps[2][ch] + ps[3][ch]);
}

extern "C" void kernel_launch(void* const* d_in, const int* in_sizes, int n_in,
                              void* d_out, int out_size, void* d_ws, size_t ws_size,
                              hipStream_t stream)
{
    const float* x     = (const float*)d_in[0];
    const float* ea    = (const float*)d_in[1];
    const int*   ei    = (const int*)d_in[2];
    const int*   batch = (const int*)d_in[3];
    const float* p1w   = (const float*)d_in[4];
    const float* p1b   = (const float*)d_in[5];
    const float* p2w   = (const float*)d_in[6];
    const float* p2b   = (const float*)d_in[7];
    const float* w1    = (const float*)d_in[8];
    const float* b1    = (const float*)d_in[9];
    const float* w2    = (const float*)d_in[10];
    const float* b2    = (const float*)d_in[11];
    const float* w3    = (const float*)d_in[12];
    const float* b3    = (const float*)d_in[13];
    const float* w4    = (const float*)d_in[14];
    const float* b4    = (const float*)d_in[15];
    float* out = (float*)d_out;
    (void)in_sizes; (void)n_in; (void)out_size; (void)ws_size;

    char* ws = (char*)d_ws;
    unsigned short* h_bf = (unsigned short*)(ws);              // 1 MB
    unsigned short* e3bf = (unsigned short*)(ws + 1048576);    // 2 MB
    float* hb            = (float*)(ws + 3145728);             // 2 MB
    unsigned short* w4p  = (unsigned short*)(ws + 5242880);    // 4 MB (swizzled, 4096 u16/slice)
    float* agg           = (float*)(ws + 9699328);             // 2 MB
    float* cnt           = (float*)(ws + 11796480);            // 16 KB (contiguous after agg)

    // 3 dispatch nodes: fused pre+edge -> nnconv -> pool.
    fused_pre_edge_kernel<<<1024, 256, 0, stream>>>(
        x, p1w, p1b, p2w, p2b, b4, h_bf, hb,
        ea, w1, b1, w2, b2, w3, b3, e3bf,
        w4, w4p, agg);
    nnconv_kernel<<<512, 256, 0, stream>>>(e3bf, h_bf, w4p, hb, ei, agg, cnt);
    pool_kernel<<<N_GRAPHS, 512, 0, stream>>>(agg, cnt, batch, out);
}

// Round 15
// 168.964 us; speedup vs baseline: 1.0395x; 1.0395x over previous
//
#include <hip/hip_runtime.h>
#include <hip/hip_bf16.h>

#define N_NODES 4096
#define N_EDGES 8192
#define N_GRAPHS 64
#define HDIM 128

typedef __attribute__((ext_vector_type(8))) short bf16x8;
typedef __attribute__((ext_vector_type(4))) float f32x4;

static __device__ __forceinline__ unsigned short f2bf(float f) {
    unsigned u = __builtin_bit_cast(unsigned, f);
    u += 0x7fffu + ((u >> 16) & 1u);
    return (unsigned short)(u >> 16);
}
static __device__ __forceinline__ float bf2f(unsigned short s) {
    unsigned u = ((unsigned)s) << 16;
    return __builtin_bit_cast(float, u);
}

// ---------------- fused pre+edge: ONE dispatch (pre->edge23 dependency removed by
// building w2/w3 B-fragments on the fly from f32 — numerically identical to the pack).
// grid 1024: [0,512) edge MLP l1+l2+l3 (16 edges each, MFMA);
//            [512,768) node MLP (+hb bias path);
//            [768,896) w4 pack (bf16 [o>>5:4][chunk:128][o&31:32][k:136]);
//            [896,1024) zero agg+cnt (replaces memset node).
__global__ __launch_bounds__(256) void fused_pre_edge_kernel(
    // node
    const float* __restrict__ x, const float* __restrict__ p1w, const float* __restrict__ p1b,
    const float* __restrict__ p2w, const float* __restrict__ p2b, const float* __restrict__ e4b,
    unsigned short* __restrict__ h_bf, float* __restrict__ hb,
    // edge
    const float* __restrict__ ea, const float* __restrict__ w1, const float* __restrict__ b1,
    const float* __restrict__ w2, const float* __restrict__ b2,
    const float* __restrict__ w3, const float* __restrict__ b3,
    unsigned short* __restrict__ e3bf,
    // w4 pack + zero
    const float* __restrict__ w4, unsigned short* __restrict__ w4perm,
    float* __restrict__ aggz)
{
    __shared__ __align__(16) char smem[33024];
    const int t = threadIdx.x;
    const int bid = blockIdx.x;

    if (bid < 512) {
        // ---- edge MLP: l1 in-block (5->128 relu, LDS bf16), l2 (128->256 relu, MFMA),
        //      l3 (256->128 relu, MFMA). B-frags converted f32->bf16 on the fly.
        float (*es)[5] = (float(*)[5])smem;                        // 320 B
        unsigned short* l1a = (unsigned short*)(smem + 320);       // [16][136] bf16, 4352 B
        unsigned short* l2a = (unsigned short*)(smem + 4672);      // [16][264] bf16, 8448 B
        const int w = t >> 6, lane = t & 63, q = lane >> 4, l15 = lane & 15;
        const int e0 = bid * 16;
        const f32x4 zero4 = (f32x4){0.f, 0.f, 0.f, 0.f};

        for (int r = t; r < 80; r += 256) es[r / 5][r % 5] = ea[e0 * 5 + r];
        __syncthreads();
        {
            int j = t & 127, eh = t >> 7;
            float wd[5];
            #pragma unroll
            for (int d = 0; d < 5; ++d) wd[d] = w1[d * 128 + j];
            float bj = b1[j];
            #pragma unroll
            for (int p = 0; p < 8; ++p) {
                int e = eh * 8 + p;
                float acc = bj;
                #pragma unroll
                for (int d = 0; d < 5; ++d) acc += es[e][d] * wd[d];
                l1a[e * 136 + j] = f2bf(fmaxf(acc, 0.f));
            }
        }
        __syncthreads();

        bf16x8 afrag[4];
        #pragma unroll
        for (int s = 0; s < 4; ++s)
            afrag[s] = *(const bf16x8*)&l1a[l15 * 136 + s * 32 + q * 8];

        // l2: M=16 N=256 K=128; wave covers o-range w*64..+64
        f32x4 acc[4];
        #pragma unroll
        for (int ob = 0; ob < 4; ++ob) acc[ob] = zero4;
        #pragma unroll
        for (int ob = 0; ob < 4; ++ob) {
            const int o = w * 64 + ob * 16 + l15;
            bf16x8 bfrag[4];
            #pragma unroll
            for (int s = 0; s < 4; ++s) {
                const int kb = s * 32 + q * 8;
                #pragma unroll
                for (int kk = 0; kk < 8; ++kk)
                    bfrag[s][kk] = (short)f2bf(w2[(kb + kk) * 256 + o]);
            }
            f32x4 tmp = __builtin_amdgcn_mfma_f32_16x16x32_bf16(afrag[0], bfrag[0], zero4, 0, 0, 0);
            tmp = __builtin_amdgcn_mfma_f32_16x16x32_bf16(afrag[1], bfrag[1], tmp, 0, 0, 0);
            tmp = __builtin_amdgcn_mfma_f32_16x16x32_bf16(afrag[2], bfrag[2], tmp, 0, 0, 0);
            acc[ob] = __builtin_amdgcn_mfma_f32_16x16x32_bf16(afrag[3], bfrag[3], tmp, 0, 0, 0);
        }
        #pragma unroll
        for (int ob = 0; ob < 4; ++ob) {
            int o = w * 64 + ob * 16 + l15;
            float bo = b2[o];
            #pragma unroll
            for (int r = 0; r < 4; ++r) {
                int e_loc = q * 4 + r;
                l2a[e_loc * 264 + o] = f2bf(fmaxf(acc[ob][r] + bo, 0.f));
            }
        }
        __syncthreads();

        // l3: M=16 N=128 K=256; wave o-range w*32..+32, 8 k-steps
        f32x4 acc3[2];
        acc3[0] = zero4; acc3[1] = zero4;
        #pragma unroll
        for (int ks = 0; ks < 8; ++ks) {
            bf16x8 a3 = *(const bf16x8*)&l2a[l15 * 264 + ks * 32 + q * 8];
            #pragma unroll
            for (int ob = 0; ob < 2; ++ob) {
                const int o = w * 32 + ob * 16 + l15;
                bf16x8 bf;
                const int kb = ks * 32 + q * 8;
                #pragma unroll
                for (int kk = 0; kk < 8; ++kk)
                    bf[kk] = (short)f2bf(w3[(kb + kk) * 128 + o]);
                acc3[ob] = __builtin_amdgcn_mfma_f32_16x16x32_bf16(a3, bf, acc3[ob], 0, 0, 0);
            }
        }
        #pragma unroll
        for (int ob = 0; ob < 2; ++ob) {
            int o = w * 32 + ob * 16 + l15;
            float bo = b3[o];
            #pragma unroll
            for (int r = 0; r < 4; ++r) {
                int e = e0 + q * 4 + r;
                e3bf[(size_t)e * 128 + o] = f2bf(fmaxf(acc3[ob][r] + bo, 0.f));
            }
        }
    } else if (bid < 768) {
        // ---- node MLP: h = relu(x@p1+b1)@p2+b2 ; hb = h @ B4
        float (*xs)[11]  = (float(*)[11])smem;           // 704 B
        float (*l1t)[16] = (float(*)[16])(smem + 704);   // 8192 B
        float (*hs)[16]  = (float(*)[16])(smem + 8896);  // 8192 B
        const int nb = bid - 512;

        for (int r = t; r < 16 * 11; r += 256) {
            int e = r / 11, d = r % 11;
            xs[e][d] = x[(nb * 16 + e) * 11 + d];
        }
        __syncthreads();
        {
            int j = t & 127;
            float wd[11];
            #pragma unroll
            for (int d = 0; d < 11; ++d) wd[d] = p1w[d * 128 + j];
            float bj = p1b[j];
            for (int p = 0; p < 8; ++p) {
                int e = p * 2 + (t >> 7);
                float acc = bj;
                #pragma unroll
                for (int d = 0; d < 11; ++d) acc += xs[e][d] * wd[d];
                l1t[j][e] = fmaxf(acc, 0.f);
            }
        }
        __syncthreads();
        {
            int j = t & 127, eh = t >> 7;
            float acc[8];
            float bj = p2b[j];
            #pragma unroll
            for (int r = 0; r < 8; ++r) acc[r] = bj;
            #pragma unroll 8
            for (int k = 0; k < 128; ++k) {
                float w = p2w[k * 128 + j];
                const float4* row = (const float4*)&l1t[k][eh * 8];
                float4 v0 = row[0], v1 = row[1];
                acc[0] += v0.x * w; acc[1] += v0.y * w; acc[2] += v0.z * w; acc[3] += v0.w * w;
                acc[4] += v1.x * w; acc[5] += v1.y * w; acc[6] += v1.z * w; acc[7] += v1.w * w;
            }
            #pragma unroll
            for (int r = 0; r < 8; ++r) {
                int e = eh * 8 + r;
                h_bf[(nb * 16 + e) * 128 + j] = f2bf(acc[r]);
                hs[j][e] = acc[r];
            }
        }
        __syncthreads();
        {
            int j = t & 127, eh = t >> 7;
            float acc[8] = {0.f,0.f,0.f,0.f,0.f,0.f,0.f,0.f};
            #pragma unroll 8
            for (int i = 0; i < 128; ++i) {
                float w = e4b[i * 128 + j];
                const float4* row = (const float4*)&hs[i][eh * 8];
                float4 v0 = row[0], v1 = row[1];
                acc[0] += v0.x * w; acc[1] += v0.y * w; acc[2] += v0.z * w; acc[3] += v0.w * w;
                acc[4] += v1.x * w; acc[5] += v1.y * w; acc[6] += v1.z * w; acc[7] += v1.w * w;
            }
            #pragma unroll
            for (int r = 0; r < 8; ++r) hb[(nb * 16 + eh * 8 + r) * 128 + j] = acc[r];
        }
    } else if (bid < 896) {
        // ---- pack e4_w into bf16 [o>>5:4][chunk i:128][o&31:32][k:136]
        unsigned short (*tt)[129] = (unsigned short(*)[129])smem;  // 33024 B
        const int i = bid - 768;
        for (int r = t; r < 16384; r += 256) {
            int k = r >> 7, o = r & 127;
            tt[o][k] = f2bf(w4[k * 16384 + i * 128 + o]);
        }
        __syncthreads();
        for (int r = t; r < 16384; r += 256) {
            int o = r >> 7, k = r & 127;
            w4perm[((size_t)(o >> 5) * 128 + i) * 4352 + (size_t)(o & 31) * 136 + k] = tt[o][k];
        }
    } else {
        // ---- zero agg (2 MB) + cnt (16 KB), contiguous: 132096 float4
        float4* dst = (float4*)aggz;
        const float4 z = make_float4(0.f, 0.f, 0.f, 0.f);
        for (int i = (bid - 896) * 256 + t; i < 132096; i += 128 * 256) dst[i] = z;
    }
}

// ---------------- fused NNConv message GEMM: v7 (measured best, 56.7 us) — byte-exact.
// block = 64 edges x 32 o; waves = (og: 16-o half) x (kpar: 32-chunk half).
// kpar pairs reduce through LDS -> ONE atomic per (e,o) per K-half (2.1M total).
// bid&7 = (osplit,ksplit) == XCD -> 557 KB slice L2-resident.
__global__ __launch_bounds__(256, 3) void nnconv_kernel(
    const unsigned short* __restrict__ e3bf, const unsigned short* __restrict__ h_bf,
    const unsigned short* __restrict__ w4perm, const float* __restrict__ hb,
    const int* __restrict__ ei, float* __restrict__ agg, float* __restrict__ cnt)
{
    __shared__ __align__(16) float ht_f[64 * 64];     // [i_local:64][e:64] f32, 16 KB
    __shared__ __align__(16) float red[2 * 64 * 16];  // [og][e_loc][l15] f32, 8 KB
    const int t = threadIdx.x;
    const int bid = blockIdx.x;
    const int osplit = bid & 3;          // 4 o-slices of 32
    const int ksplit = (bid >> 2) & 1;   // 2 K-halves of 64 chunks
    const int etile  = bid >> 3;         // 128 tiles of 64 edges
    const int w = t >> 6, lane = t & 63, q = lane >> 4, l15 = lane & 15;
    const int og   = w & 1;              // o-16 group
    const int kpar = w >> 1;             // 32-chunk half within the K-half
    const int e0 = etile * 64;
    const int o0 = osplit * 32;
    const int i0 = ksplit * 64;

    // A fragments: this block's 64 e3 rows (full K=128), constant across all chunks.
    bf16x8 afrag[4][4];
    #pragma unroll
    for (int mb = 0; mb < 4; ++mb)
        #pragma unroll
        for (int s = 0; s < 4; ++s) {
            int row = e0 + mb * 16 + l15;
            afrag[mb][s] = *(const bf16x8*)(e3bf + (size_t)row * 128 + s * 32 + q * 8);
        }
    #pragma unroll
    for (int mb = 0; mb < 4; ++mb)
        #pragma unroll
        for (int s = 0; s < 4; ++s)
            asm volatile("" : "+v"(afrag[mb][s]));
    asm volatile("" ::: "memory");

    {   // gather h rows through src[e]: 4 threads/edge, this K-half only, f32 transposed
        int r = t >> 2, part = t & 3;
        int s = ei[e0 + r];
        #pragma unroll
        for (int u = 0; u < 2; ++u) {
            uint4 v = *(const uint4*)(h_bf + (size_t)s * 128 + i0 + part * 16 + u * 8);
            const unsigned short* pv = (const unsigned short*)&v;
            #pragma unroll
            for (int j = 0; j < 8; ++j)
                ht_f[(part * 16 + u * 8 + j) * 64 + r] = bf2f(pv[j]);
        }
    }

    f32x4 acc[4];
    #pragma unroll
    for (int mb = 0; mb < 4; ++mb) acc[mb] = (f32x4){0.f, 0.f, 0.f, 0.f};
    const f32x4 zero4 = (f32x4){0.f, 0.f, 0.f, 0.f};

    __syncthreads();   // ht_f ready

    // Barrier-free K-loop: 32 chunks per wave, B-frags straight from global.
    const unsigned short* bbase =
        w4perm + ((size_t)osplit * 128 + i0 + kpar * 32) * 4352
               + (size_t)(og * 16 + l15) * 136 + q * 8;
    #pragma unroll 2
    for (int c = 0; c < 32; ++c) {
        const unsigned short* bp = bbase + (size_t)c * 4352;
        bf16x8 bfrag[4];
        #pragma unroll
        for (int s = 0; s < 4; ++s)
            bfrag[s] = *(const bf16x8*)(bp + s * 32);
        const int cg = kpar * 32 + c;    // i_local for ht_f
        #pragma unroll
        for (int mb = 0; mb < 4; ++mb) {
            f32x4 hv = *(const f32x4*)&ht_f[cg * 64 + mb * 16 + q * 4];
            f32x4 tmp = __builtin_amdgcn_mfma_f32_16x16x32_bf16(afrag[mb][0], bfrag[0], zero4, 0, 0, 0);
            tmp = __builtin_amdgcn_mfma_f32_16x16x32_bf16(afrag[mb][1], bfrag[1], tmp, 0, 0, 0);
            tmp = __builtin_amdgcn_mfma_f32_16x16x32_bf16(afrag[mb][2], bfrag[2], tmp, 0, 0, 0);
            tmp = __builtin_amdgcn_mfma_f32_16x16x32_bf16(afrag[mb][3], bfrag[3], tmp, 0, 0, 0);
            #pragma unroll
            for (int r = 0; r < 4; ++r)
                acc[mb][r] += hv[r] * tmp[r];
        }
    }

    // kpar reduction through LDS, then ONE atomic per (e,o) per K-half.
    if (kpar == 1) {
        #pragma unroll
        for (int mb = 0; mb < 4; ++mb)
            #pragma unroll
            for (int r = 0; r < 4; ++r)
                red[(og * 64 + mb * 16 + q * 4 + r) * 16 + l15] = acc[mb][r];
    }
    __syncthreads();
    if (kpar == 0) {
        #pragma unroll
        for (int mb = 0; mb < 4; ++mb) {
            #pragma unroll
            for (int r = 0; r < 4; ++r) {
                int e_loc = mb * 16 + q * 4 + r;
                int e = e0 + e_loc;
                int de = ei[N_EDGES + e];
                int se = ei[e];
                int o = o0 + og * 16 + l15;
                float v = acc[mb][r] + red[(og * 64 + e_loc) * 16 + l15];
                if (ksplit == 0) v += hb[(size_t)se * 128 + o];
                if (osplit == 0 && ksplit == 0 && og == 0 && l15 == 0)
                    atomicAdd(&cnt[de], 1.0f);
                atomicAdd(&agg[(size_t)de * 128 + o], v);
            }
        }
    }
}

// ---------------- scatter-mean finalize + global add pool.
// batch is SORTED -> one block per graph, binary-search bounds, direct store.
// 512 threads: 4-way node-split (th) x 128 channels (ch) + LDS reduce.
__global__ __launch_bounds__(512) void pool_kernel(
    const float* __restrict__ agg, const float* __restrict__ cnt,
    const int* __restrict__ batch, float* __restrict__ out)
{
    __shared__ float ps[4][128];
    const int g = blockIdx.x;
    const int ch = threadIdx.x & 127, th = threadIdx.x >> 7;
    int lo = 0, hi = N_NODES;
    while (lo < hi) { int m = (lo + hi) >> 1; if (batch[m] < g) lo = m + 1; else hi = m; }
    const int n_lo = lo;
    int lo2 = n_lo, hi2 = N_NODES;
    while (lo2 < hi2) { int m = (lo2 + hi2) >> 1; if (batch[m] < g + 1) lo2 = m + 1; else hi2 = m; }
    const int n_hi = lo2;

    float s = 0.f;
    for (int n = n_lo + th; n < n_hi; n += 4) {
        float c = cnt[n];
        c = c > 1.f ? c : 1.f;
        s += agg[n * 128 + ch] / c;
    }
    ps[th][ch] = s;
    __syncthreads();
    if (th == 0)
        out[g * 128 + ch] = (ps[0][ch] + ps[1][ch]) + (ps[2][ch] + ps[3][ch]);
}

extern "C" void kernel_launch(void* const* d_in, const int* in_sizes, int n_in,
                              void* d_out, int out_size, void* d_ws, size_t ws_size,
                              hipStream_t stream)
{
    const float* x     = (const float*)d_in[0];
    const float* ea    = (const float*)d_in[1];
    const int*   ei    = (const int*)d_in[2];
    const int*   batch = (const int*)d_in[3];
    const float* p1w   = (const float*)d_in[4];
    const float* p1b   = (const float*)d_in[5];
    const float* p2w   = (const float*)d_in[6];
    const float* p2b   = (const float*)d_in[7];
    const float* w1    = (const float*)d_in[8];
    const float* b1    = (const float*)d_in[9];
    const float* w2    = (const float*)d_in[10];
    const float* b2    = (const float*)d_in[11];
    const float* w3    = (const float*)d_in[12];
    const float* b3    = (const float*)d_in[13];
    const float* w4    = (const float*)d_in[14];
    const float* b4    = (const float*)d_in[15];
    float* out = (float*)d_out;
    (void)in_sizes; (void)n_in; (void)out_size; (void)ws_size;

    char* ws = (char*)d_ws;
    unsigned short* h_bf = (unsigned short*)(ws);              // 1 MB
    unsigned short* e3bf = (unsigned short*)(ws + 1048576);    // 2 MB
    float* hb            = (float*)(ws + 3145728);             // 2 MB
    unsigned short* w4p  = (unsigned short*)(ws + 5242880);    // 4.25 MB
    float* agg           = (float*)(ws + 9699328);             // 2 MB
    float* cnt           = (float*)(ws + 11796480);            // 16 KB (contiguous after agg)

    // 3 dispatch nodes: fused pre+edge -> nnconv -> pool.
    fused_pre_edge_kernel<<<1024, 256, 0, stream>>>(
        x, p1w, p1b, p2w, p2b, b4, h_bf, hb,
        ea, w1, b1, w2, b2, w3, b3, e3bf,
        w4, w4p, agg);
    nnconv_kernel<<<1024, 256, 0, stream>>>(e3bf, h_bf, w4p, hb, ei, agg, cnt);
    pool_kernel<<<N_GRAPHS, 512, 0, stream>>>(agg, cnt, batch, out);
}